// Round 13
// baseline (487.864 us; speedup 1.0000x reference)
//
#include <hip/hip_runtime.h>
#include <stdint.h>

#define BB 4096
#define TT 512
#define HH 32
#define SS 4

typedef float v2f __attribute__((ext_vector_type(2)));

__device__ __forceinline__ float fast_sigm(float a) {
  return __builtin_amdgcn_rcpf(1.0f + __expf(-a));      // v_exp + v_rcp
}
__device__ __forceinline__ float fast_tanh(float y) {
  return 1.0f - 2.0f * __builtin_amdgcn_rcpf(__expf(2.0f * y) + 1.0f);
}
// packed 2xf32 FMA (VOP3P, validated r7/r11): c = a*b + c elementwise
__device__ __forceinline__ v2f pkfma(v2f a, v2f b, v2f c) {
  asm("v_pk_fma_f32 %0, %1, %2, %0" : "+v"(c) : "v"(a), "v"(b));
  return c;
}

// NB=2 amortization: every weight value fetched from LDS feeds TWO batches.
// Wave = 2 groups x 32 lanes; lane j of group g owns h[j] for batches bA,bB.
// Weight stream per wave-step identical to r11 (24 per-lane b128, group-deduped)
// but VALU per fetched byte doubles -> DS pipe drops below VALU. 1024 waves
// (1/SIMD). All h traffic same-wave (rows owned exclusively by this wave).
__global__ void __launch_bounds__(256)
gru_kernel(const float* __restrict__ x, const float* __restrict__ h0,
           const float* __restrict__ w_ih, const float* __restrict__ w_hh,
           const float* __restrict__ b_ih, const float* __restrict__ b_hh,
           const float* __restrict__ w_proj, const float* __restrict__ b_proj,
           float* __restrict__ out) {
  const int tid  = threadIdx.x;
  const int wid  = tid >> 6;        // wave 0..3
  const int lane = tid & 63;
  const int g    = lane >> 5;       // group within wave
  const int j    = lane & 31;       // h index owned by this lane
  const int rA   = wid * 4 + g * 2; // LDS h row, batch A
  const int rB   = rA + 1;
  const int bA   = blockIdx.x * 16 + rA;
  const int bB   = bA + 1;
  const int s_idx = j & 3;          // proj channel
  const int c_idx = j >> 2;         // proj h-chunk

  __shared__ float wl[96][36];      // w_hh rows, stride 36 (validated r11: 0 conflicts)
  __shared__ float hl[16][36];      // h rows, one per batch of the block

  // ---- cooperative weight staging (once) ----
  for (int idx = tid; idx < 96 * 8; idx += 256) {
    const int r = idx >> 3, q = idx & 7;
    *(float4*)&wl[r][q * 4] = *(const float4*)(w_hh + r * HH + q * 4);
  }
  __syncthreads();

  // ---- per-lane invariants ----
  const float4* wih4 = (const float4*)w_ih;
  const float4 wir = wih4[j], wiz = wih4[32 + j], win = wih4[64 + j];
  const float bir = b_ih[j], biz = b_ih[32 + j], bin_ = b_ih[64 + j];
  const float bhr = b_hh[j], bhz = b_hh[32 + j], bhn = b_hh[64 + j];
  const float4 wp = ((const float4*)w_proj)[s_idx * 8 + c_idx];
  const float bp = b_proj[s_idx];

  const float* wrp = &wl[j][0];
  const float* wzp = &wl[32 + j][0];
  const float* wnp = &wl[64 + j][0];
  float* lrowA = &hl[rA][0];
  float* lrowB = &hl[rB][0];
  const float* hcA = lrowA + (c_idx << 2);
  const float* hcB = lrowB + (c_idx << 2);

  float hA = h0[(size_t)bA * HH + j];
  float hB = h0[(size_t)bB * HH + j];
  lrowA[j] = hA;
  lrowB[j] = hB;

  const float4* xpA = (const float4*)(x + (size_t)bA * TT * 4);
  const float4* xpB = (const float4*)(x + (size_t)bB * TT * 4);
  float* outA = out + (size_t)bA * TT * SS;
  float* outB = out + (size_t)bB * TT * SS;

  float4 xvA = xpA[0];
  float4 xvB = xpB[0];

  for (int t = 0; t <= TT; ++t) {
    // proj chunks of h_{t-1} (read before this step's h write)
    const float4 qA = *(const float4*)hcA;
    const float4 qB = *(const float4*)hcB;

    // deferred projection: out[t-1] = proj(h after step t-1)
    if (t > 0) {
      float vA = fmaf(wp.x, qA.x, fmaf(wp.y, qA.y, fmaf(wp.z, qA.z, wp.w * qA.w)));
      float vB = fmaf(wp.x, qB.x, fmaf(wp.y, qB.y, fmaf(wp.z, qB.z, wp.w * qB.w)));
      vA += __shfl_xor(vA, 4, 64);  vB += __shfl_xor(vB, 4, 64);
      vA += __shfl_xor(vA, 8, 64);  vB += __shfl_xor(vB, 8, 64);
      vA += __shfl_xor(vA, 16, 64); vB += __shfl_xor(vB, 16, 64);
      if (c_idx == 0) {
        outA[(t - 1) * SS + s_idx] = vA + bp;
        outB[(t - 1) * SS + s_idx] = vB + bp;
      }
    }
    if (t == TT) break;

    const int tn = (t + 1 < TT) ? (t + 1) : t;
    float4 xvnA = xpA[tn];                        // next-step x prefetch
    float4 xvnB = xpB[tn];

    // input gates packed across batches: lane computes (gate_A, gate_B) pairs
    v2f xr2 = (v2f){bir, bir}, xz2 = (v2f){biz, biz}, xn2 = (v2f){bin_, bin_};
    xr2 = pkfma((v2f){wir.x, wir.x}, (v2f){xvA.x, xvB.x}, xr2);
    xr2 = pkfma((v2f){wir.y, wir.y}, (v2f){xvA.y, xvB.y}, xr2);
    xr2 = pkfma((v2f){wir.z, wir.z}, (v2f){xvA.z, xvB.z}, xr2);
    xr2 = pkfma((v2f){wir.w, wir.w}, (v2f){xvA.w, xvB.w}, xr2);
    xz2 = pkfma((v2f){wiz.x, wiz.x}, (v2f){xvA.x, xvB.x}, xz2);
    xz2 = pkfma((v2f){wiz.y, wiz.y}, (v2f){xvA.y, xvB.y}, xz2);
    xz2 = pkfma((v2f){wiz.z, wiz.z}, (v2f){xvA.z, xvB.z}, xz2);
    xz2 = pkfma((v2f){wiz.w, wiz.w}, (v2f){xvA.w, xvB.w}, xz2);
    xn2 = pkfma((v2f){win.x, win.x}, (v2f){xvA.x, xvB.x}, xn2);
    xn2 = pkfma((v2f){win.y, win.y}, (v2f){xvA.y, xvB.y}, xn2);
    xn2 = pkfma((v2f){win.z, win.z}, (v2f){xvA.z, xvB.z}, xn2);
    xn2 = pkfma((v2f){win.w, win.w}, (v2f){xvA.w, xvB.w}, xn2);

    // hidden GEMV: weights read ONCE, used for BOTH batches (96 pkfma)
    v2f aRA = (v2f){bhr, 0.f}, aZA = (v2f){bhz, 0.f}, aNA = (v2f){bhn, 0.f};
    v2f aRB = (v2f){bhr, 0.f}, aZB = (v2f){bhz, 0.f}, aNB = (v2f){bhn, 0.f};
#pragma unroll
    for (int kq = 0; kq < 8; ++kq) {
      const float4 hvA4 = *(const float4*)(lrowA + kq * 4);  // broadcast/group
      const float4 hvB4 = *(const float4*)(lrowB + kq * 4);
      const float4 qr = *(const float4*)(wrp + kq * 4);      // per-lane rows
      const float4 qz = *(const float4*)(wzp + kq * 4);
      const float4 qn = *(const float4*)(wnp + kq * 4);
      const v2f r01 = (v2f){qr.x, qr.y}, r23 = (v2f){qr.z, qr.w};
      const v2f z01 = (v2f){qz.x, qz.y}, z23 = (v2f){qz.z, qz.w};
      const v2f n01 = (v2f){qn.x, qn.y}, n23 = (v2f){qn.z, qn.w};
      const v2f hA01 = (v2f){hvA4.x, hvA4.y}, hA23 = (v2f){hvA4.z, hvA4.w};
      const v2f hB01 = (v2f){hvB4.x, hvB4.y}, hB23 = (v2f){hvB4.z, hvB4.w};
      aRA = pkfma(r01, hA01, aRA); aRA = pkfma(r23, hA23, aRA);
      aZA = pkfma(z01, hA01, aZA); aZA = pkfma(z23, hA23, aZA);
      aNA = pkfma(n01, hA01, aNA); aNA = pkfma(n23, hA23, aNA);
      aRB = pkfma(r01, hB01, aRB); aRB = pkfma(r23, hB23, aRB);
      aZB = pkfma(z01, hB01, aZB); aZB = pkfma(z23, hB23, aZB);
      aNB = pkfma(n01, hB01, aNB); aNB = pkfma(n23, hB23, aNB);
    }

    // gates + update, batch A
    {
      const float r  = fast_sigm(xr2.x + aRA.x + aRA.y);
      const float zz = fast_sigm(xz2.x + aZA.x + aZA.y);
      const float nn = fast_tanh(fmaf(r, aNA.x + aNA.y, xn2.x));
      hA = fmaf(zz, hA - nn, nn);
      lrowA[j] = hA;
    }
    // gates + update, batch B
    {
      const float r  = fast_sigm(xr2.y + aRB.x + aRB.y);
      const float zz = fast_sigm(xz2.y + aZB.x + aZB.y);
      const float nn = fast_tanh(fmaf(r, aNB.x + aNB.y, xn2.y));
      hB = fmaf(zz, hB - nn, nn);
      lrowB[j] = hB;
    }

    xvA = xvnA;
    xvB = xvnB;
  }

  // hn output: [1, B, H] appended after state (f32)
  out[(size_t)BB * TT * SS + (size_t)bA * HH + j] = hA;
  out[(size_t)BB * TT * SS + (size_t)bB * HH + j] = hB;
}

extern "C" void kernel_launch(void* const* d_in, const int* in_sizes, int n_in,
                              void* d_out, int out_size, void* d_ws, size_t ws_size,
                              hipStream_t stream) {
  const float* x      = (const float*)d_in[0];
  const float* h0     = (const float*)d_in[1];
  const float* w_ih   = (const float*)d_in[2];
  const float* w_hh   = (const float*)d_in[3];
  const float* b_ih   = (const float*)d_in[4];
  const float* b_hh   = (const float*)d_in[5];
  const float* w_proj = (const float*)d_in[6];
  const float* b_proj = (const float*)d_in[7];
  float* out = (float*)d_out;

  dim3 grid(BB / 16), block(256);
  hipLaunchKernelGGL(gru_kernel, grid, block, 0, stream,
                     x, h0, w_ih, w_hh, b_ih, b_hh, w_proj, b_proj, out);
}

// Round 14
// 417.121 us; speedup vs baseline: 1.1696x; 1.1696x over previous
//
#include <hip/hip_runtime.h>
#include <stdint.h>

#define BB 4096
#define TT 512
#define HH 32
#define SS 4

typedef float v2f __attribute__((ext_vector_type(2)));

__device__ __forceinline__ float fast_sigm(float a) {
  return __builtin_amdgcn_rcpf(1.0f + __expf(-a));      // v_exp + v_rcp
}
__device__ __forceinline__ float fast_tanh(float y) {
  return 1.0f - 2.0f * __builtin_amdgcn_rcpf(__expf(2.0f * y) + 1.0f);
}
// packed 2xf32 FMA (VOP3P, validated r7/r11): c = a*b + c elementwise
__device__ __forceinline__ v2f pkfma(v2f a, v2f b, v2f c) {
  asm("v_pk_fma_f32 %0, %1, %2, %0" : "+v"(c) : "v"(a), "v"(b));
  return c;
}
// acc += w4 .* (hA,hB)   (two pkfma)
#define FMA4(acc, w4, hA, hB)                                                  \
  acc = pkfma((v2f){(w4).x, (w4).y}, (hA), acc);                               \
  acc = pkfma((v2f){(w4).z, (w4).w}, (hB), acc)

// r11 structure (LDS f32 weight streaming, 2 batches/wave, 2048 waves) with the
// latency fixed: waves_per_eu(2,2) drops the occupancy target to the real value
// (2 waves/SIMD) so the scheduler may hold a deep prefetch, and the loop body is
// hand-chunked — 9 h-reads + rotating 4-quad weight buffers — so every ds_read
// has >=24 FMAs between issue and consumption. Peak live set ~95 regs, i.e.
// deliberately under the empirical 96-VGPR cap seen in r5-r12.
__global__ void __attribute__((amdgpu_flat_work_group_size(256, 256)))
__attribute__((amdgpu_waves_per_eu(2, 2)))
gru_kernel(const float* __restrict__ x, const float* __restrict__ h0,
           const float* __restrict__ w_ih, const float* __restrict__ w_hh,
           const float* __restrict__ b_ih, const float* __restrict__ b_hh,
           const float* __restrict__ w_proj, const float* __restrict__ b_proj,
           float* __restrict__ out) {
  const int tid  = threadIdx.x;
  const int wid  = tid >> 6;        // wave 0..3
  const int lane = tid & 63;
  const int g    = lane >> 5;       // batch within wave
  const int j    = lane & 31;       // h index owned by this lane
  const int row  = wid * 2 + g;     // LDS h row 0..7
  const int b    = blockIdx.x * 8 + row;
  const int s_idx = j & 3;          // proj channel
  const int c_idx = j >> 2;         // proj h-chunk

  __shared__ float wl[96][36];      // w_hh rows, stride 36 (r11: 0 conflicts)
  __shared__ float hl[8][36];       // h rows, one per batch

  // ---- cooperative weight staging (once) ----
  for (int idx = tid; idx < 96 * 8; idx += 256) {
    const int r = idx >> 3, q = idx & 7;
    *(float4*)&wl[r][q * 4] = *(const float4*)(w_hh + r * HH + q * 4);
  }
  __syncthreads();

  // ---- per-lane invariants ----
  const float4* wih4 = (const float4*)w_ih;
  const float4 wir = wih4[j], wiz = wih4[32 + j], win = wih4[64 + j];
  const float bir = b_ih[j], biz = b_ih[32 + j], bin_ = b_ih[64 + j];
  const float bhr = b_hh[j], bhz = b_hh[32 + j], bhn = b_hh[64 + j];
  const float4 wp = ((const float4*)w_proj)[s_idx * 8 + c_idx];
  const float bp = b_proj[s_idx];

  const float4* wr4 = (const float4*)&wl[j][0];
  const float4* wz4 = (const float4*)&wl[32 + j][0];
  const float4* wn4 = (const float4*)&wl[64 + j][0];
  float* lrow = &hl[row][0];
  const float4* lrow4 = (const float4*)lrow;
  const float* hc_addr = lrow + (c_idx << 2);

  float h_self = h0[(size_t)b * HH + j];
  lrow[j] = h_self;

  const float4* xp = (const float4*)(x + (size_t)b * TT * 4);
  float* outp = out + (size_t)b * TT * SS;

  float4 xv = xp[0];

  for (int t = 0; t <= TT; ++t) {
    // ---- issue ALL h reads + first weight chunk, pinned ahead of compute ----
    float4 hq0 = lrow4[0], hq1 = lrow4[1], hq2 = lrow4[2], hq3 = lrow4[3];
    float4 hq4 = lrow4[4], hq5 = lrow4[5], hq6 = lrow4[6], hq7 = lrow4[7];
    float4 hcv = *(const float4*)hc_addr;
    float4 wa0 = wr4[0], wa1 = wr4[1], wa2 = wr4[2], wa3 = wr4[3];
    __builtin_amdgcn_sched_barrier(0);

    // deferred projection: out[t-1] = proj(h after step t-1)
    if (t > 0) {
      float v = fmaf(wp.x, hcv.x, fmaf(wp.y, hcv.y,
                fmaf(wp.z, hcv.z, wp.w * hcv.w)));
      v += __shfl_xor(v, 4, 64);
      v += __shfl_xor(v, 8, 64);
      v += __shfl_xor(v, 16, 64);
      if (c_idx == 0) outp[(t - 1) * SS + s_idx] = v + bp;
    }
    if (t == TT) break;

    float4 xvn = xp[(t + 1 < TT) ? (t + 1) : t];   // next-step x prefetch

    // input gates (independent of h — fills the h-read latency shadow)
    float xr = fmaf(wir.x, xv.x, fmaf(wir.y, xv.y, fmaf(wir.z, xv.z, fmaf(wir.w, xv.w, bir))));
    float xz = fmaf(wiz.x, xv.x, fmaf(wiz.y, xv.y, fmaf(wiz.z, xv.z, fmaf(wiz.w, xv.w, biz))));
    float xn = fmaf(win.x, xv.x, fmaf(win.y, xv.y, fmaf(win.z, xv.z, fmaf(win.w, xv.w, bin_))));

    // h quads as v2f pairs (register re-views, no moves)
    const v2f h0p = (v2f){hq0.x, hq0.y}, h0q = (v2f){hq0.z, hq0.w};
    const v2f h1p = (v2f){hq1.x, hq1.y}, h1q = (v2f){hq1.z, hq1.w};
    const v2f h2p = (v2f){hq2.x, hq2.y}, h2q = (v2f){hq2.z, hq2.w};
    const v2f h3p = (v2f){hq3.x, hq3.y}, h3q = (v2f){hq3.z, hq3.w};
    const v2f h4p = (v2f){hq4.x, hq4.y}, h4q = (v2f){hq4.z, hq4.w};
    const v2f h5p = (v2f){hq5.x, hq5.y}, h5q = (v2f){hq5.z, hq5.w};
    const v2f h6p = (v2f){hq6.x, hq6.y}, h6q = (v2f){hq6.z, hq6.w};
    const v2f h7p = (v2f){hq7.x, hq7.y}, h7q = (v2f){hq7.z, hq7.w};

    // ---- chunked GEMV: rotate wa/wb 4-quad buffers; reads lead uses by 24 FMA ----
    v2f aR = (v2f){bhr, 0.f}, aZ = (v2f){bhz, 0.f}, aN = (v2f){bhn, 0.f};

    float4 wb0 = wr4[4], wb1 = wr4[5], wb2 = wr4[6], wb3 = wr4[7];
    FMA4(aR, wa0, h0p, h0q); FMA4(aR, wa1, h1p, h1q);
    FMA4(aR, wa2, h2p, h2q); FMA4(aR, wa3, h3p, h3q);

    wa0 = wz4[0]; wa1 = wz4[1]; wa2 = wz4[2]; wa3 = wz4[3];
    FMA4(aR, wb0, h4p, h4q); FMA4(aR, wb1, h5p, h5q);
    FMA4(aR, wb2, h6p, h6q); FMA4(aR, wb3, h7p, h7q);

    wb0 = wz4[4]; wb1 = wz4[5]; wb2 = wz4[6]; wb3 = wz4[7];
    FMA4(aZ, wa0, h0p, h0q); FMA4(aZ, wa1, h1p, h1q);
    FMA4(aZ, wa2, h2p, h2q); FMA4(aZ, wa3, h3p, h3q);

    wa0 = wn4[0]; wa1 = wn4[1]; wa2 = wn4[2]; wa3 = wn4[3];
    FMA4(aZ, wb0, h4p, h4q); FMA4(aZ, wb1, h5p, h5q);
    FMA4(aZ, wb2, h6p, h6q); FMA4(aZ, wb3, h7p, h7q);

    wb0 = wn4[4]; wb1 = wn4[5]; wb2 = wn4[6]; wb3 = wn4[7];
    FMA4(aN, wa0, h0p, h0q); FMA4(aN, wa1, h1p, h1q);
    FMA4(aN, wa2, h2p, h2q); FMA4(aN, wa3, h3p, h3q);
    FMA4(aN, wb0, h4p, h4q); FMA4(aN, wb1, h5p, h5q);
    FMA4(aN, wb2, h6p, h6q); FMA4(aN, wb3, h7p, h7q);

    const float hr = aR.x + aR.y;
    const float hz = aZ.x + aZ.y;
    const float hn = aN.x + aN.y;

    const float r  = fast_sigm(xr + hr);
    const float zz = fast_sigm(xz + hz);
    const float nn = fast_tanh(fmaf(r, hn, xn));
    const float hnew = fmaf(zz, h_self - nn, nn);  // (1-z)n + z h
    h_self = hnew;

    lrow[j] = hnew;   // publish h_t (same-wave, in-order DS pipe)

    xv = xvn;
  }

  // hn output: [1, B, H] appended after state (f32)
  out[(size_t)BB * TT * SS + (size_t)b * HH + j] = h_self;
}

extern "C" void kernel_launch(void* const* d_in, const int* in_sizes, int n_in,
                              void* d_out, int out_size, void* d_ws, size_t ws_size,
                              hipStream_t stream) {
  const float* x      = (const float*)d_in[0];
  const float* h0     = (const float*)d_in[1];
  const float* w_ih   = (const float*)d_in[2];
  const float* w_hh   = (const float*)d_in[3];
  const float* b_ih   = (const float*)d_in[4];
  const float* b_hh   = (const float*)d_in[5];
  const float* w_proj = (const float*)d_in[6];
  const float* b_proj = (const float*)d_in[7];
  float* out = (float*)d_out;

  dim3 grid(BB / 8), block(256);
  hipLaunchKernelGGL(gru_kernel, grid, block, 0, stream,
                     x, h0, w_ih, w_hh, b_ih, b_hh, w_proj, b_proj, out);
}